// Round 3
// baseline (389.772 us; speedup 1.0000x reference)
//
#include <hip/hip_runtime.h>

#define TT 256
#define BB 512
#define DD 128
#define HH 50
#define KK 5
#define AA 4
#define GSTRIDE 52
#define CTS 66  // ct LDS row stride (floats): banks (2r+c)%32 -> <=2-way, free

// ---------------- K0: weight prep (transpose + pad) ----------------
__global__ void k0_prep(const float* __restrict__ W_in,
                        const float* __restrict__ W_ctx,
                        float* __restrict__ WT,
                        float* __restrict__ WHT) {
  int i = blockIdx.x * 256 + threadIdx.x;
  if (i < DD * 52) {
    int j = i / 52, h = i % 52;
    WT[i] = (h < HH) ? W_in[h * DD + j] : 0.f;
  }
  if (i < HH * 52) {
    int j = i / 52, h = i % 52;
    WHT[i] = (h < HH) ? W_ctx[h * (2 * HH) + HH + j] : 0.f;
  }
}

// ---------------- K1a: h = relu(x @ W_in^T + b_in) ----------------
__global__ __launch_bounds__(256) void k1a(const float* __restrict__ x,
                                           const float* __restrict__ WT,
                                           const float* __restrict__ b_in,
                                           float* __restrict__ hbuf) {
  const int row = blockIdx.x * 256 + threadIdx.x;
  const float* __restrict__ xr = x + (size_t)row * DD;

  float hacc[HH];
#pragma unroll
  for (int h = 0; h < HH; ++h) hacc[h] = b_in[h];

#pragma unroll 1
  for (int j = 0; j < DD; j += 4) {
    const float4 xv = *reinterpret_cast<const float4*>(xr + j);
    const float* __restrict__ w0 = WT + (j + 0) * 52;
    const float* __restrict__ w1 = WT + (j + 1) * 52;
    const float* __restrict__ w2 = WT + (j + 2) * 52;
    const float* __restrict__ w3 = WT + (j + 3) * 52;
#pragma unroll
    for (int h = 0; h < HH; ++h) {
      float t0 = fmaf(xv.x, w0[h], hacc[h]);
      float t1 = fmaf(xv.y, w1[h], t0);
      float t2 = fmaf(xv.z, w2[h], t1);
      hacc[h] = fmaf(xv.w, w3[h], t2);
    }
  }

  float* __restrict__ hr = hbuf + (size_t)row * GSTRIDE;
#pragma unroll
  for (int h = 0; h < 48; h += 4) {
    *reinterpret_cast<float4*>(hr + h) =
        make_float4(fmaxf(hacc[h], 0.f), fmaxf(hacc[h + 1], 0.f),
                    fmaxf(hacc[h + 2], 0.f), fmaxf(hacc[h + 3], 0.f));
  }
  *reinterpret_cast<float2*>(hr + 48) =
      make_float2(fmaxf(hacc[48], 0.f), fmaxf(hacc[49], 0.f));
}

// ---------------- K1b: g = h @ Wh^T + b_ctx ----------------
__global__ __launch_bounds__(256) void k1b(const float* __restrict__ hbuf,
                                           const float* __restrict__ WHT,
                                           const float* __restrict__ b_ctx,
                                           float* __restrict__ g) {
  const int row = blockIdx.x * 256 + threadIdx.x;
  const float* __restrict__ hr = hbuf + (size_t)row * GSTRIDE;

  float gacc[HH];
#pragma unroll
  for (int h = 0; h < HH; ++h) gacc[h] = b_ctx[h];

#pragma unroll 1
  for (int j0 = 0; j0 < 48; j0 += 4) {
    const float4 h4 = *reinterpret_cast<const float4*>(hr + j0);
#pragma unroll
    for (int u = 0; u < 4; ++u) {
      const float hv = (u == 0) ? h4.x : (u == 1) ? h4.y : (u == 2) ? h4.z : h4.w;
      const float* __restrict__ wh = WHT + (j0 + u) * 52;
#pragma unroll
      for (int h = 0; h < HH; ++h) gacc[h] = fmaf(hv, wh[h], gacc[h]);
    }
  }
  {
    const float2 h2 = *reinterpret_cast<const float2*>(hr + 48);
    const float* __restrict__ w48 = WHT + 48 * 52;
    const float* __restrict__ w49 = WHT + 49 * 52;
#pragma unroll
    for (int h = 0; h < HH; ++h)
      gacc[h] = fmaf(h2.y, w49[h], fmaf(h2.x, w48[h], gacc[h]));
  }

  float* __restrict__ gr = g + (size_t)row * GSTRIDE;
#pragma unroll
  for (int h = 0; h < 48; h += 4) {
    *reinterpret_cast<float4*>(gr + h) =
        make_float4(gacc[h], gacc[h + 1], gacc[h + 2], gacc[h + 3]);
  }
  *reinterpret_cast<float2*>(gr + 48) = make_float2(gacc[48], gacc[49]);
}

// ---------------- K2: per-batch recurrence (512 blocks x 1 wave) -----------
// c broadcast via v_readlane (pure VALU, no LDS in the serial chain).
// lanes 0-49: c; 50-54: keys; 55-59: q (ride the same dot for free).
__global__ __launch_bounds__(64) void k2_rec(
    const float* __restrict__ g, const float* __restrict__ W_ctx,
    const float* __restrict__ W_key, const float* __restrict__ b_key,
    const float* __restrict__ W_q, const float* __restrict__ b_q,
    const float* __restrict__ first_context, float* __restrict__ ctxg,
    float* __restrict__ keyg, float* __restrict__ qg) {
  const int b = blockIdx.x;
  const int lane = threadIdx.x;

  float wrow[HH];
  float bias = 0.f;
  if (lane < HH) {
#pragma unroll
    for (int j = 0; j < HH; ++j) wrow[j] = W_ctx[lane * (2 * HH) + j];
  } else if (lane < HH + KK) {
#pragma unroll
    for (int j = 0; j < HH; ++j) wrow[j] = W_key[(lane - HH) * HH + j];
    bias = b_key[lane - HH];
  } else if (lane < HH + 2 * KK) {
#pragma unroll
    for (int j = 0; j < HH; ++j) wrow[j] = W_q[(lane - HH - KK) * HH + j];
    bias = b_q[lane - HH - KK];
  } else {
#pragma unroll
    for (int j = 0; j < HH; ++j) wrow[j] = 0.f;
  }

  float c_reg = (lane < HH) ? first_context[lane] : 0.f;
  if (lane < HH) ctxg[((size_t)b * 257 + 0) * HH + lane] = c_reg;

  float gv0 = (lane < HH) ? g[((size_t)0 * BB + b) * GSTRIDE + lane] : 0.f;
  float gv1 = (lane < HH) ? g[((size_t)1 * BB + b) * GSTRIDE + lane] : 0.f;

  for (int t = 0; t <= TT; ++t) {
    float gvn = 0.f;
    if (lane < HH && (t + 2) < TT)
      gvn = g[((size_t)(t + 2) * BB + b) * GSTRIDE + lane];

    float a0 = 0.f, a1 = 0.f, a2 = 0.f, a3 = 0.f;
    const int ci = __float_as_int(c_reg);
#pragma unroll
    for (int j = 0; j < 48; j += 4) {
      a0 = fmaf(wrow[j + 0], __int_as_float(__builtin_amdgcn_readlane(ci, j + 0)), a0);
      a1 = fmaf(wrow[j + 1], __int_as_float(__builtin_amdgcn_readlane(ci, j + 1)), a1);
      a2 = fmaf(wrow[j + 2], __int_as_float(__builtin_amdgcn_readlane(ci, j + 2)), a2);
      a3 = fmaf(wrow[j + 3], __int_as_float(__builtin_amdgcn_readlane(ci, j + 3)), a3);
    }
    a0 = fmaf(wrow[48], __int_as_float(__builtin_amdgcn_readlane(ci, 48)), a0);
    a1 = fmaf(wrow[49], __int_as_float(__builtin_amdgcn_readlane(ci, 49)), a1);
    const float acc = (a0 + a1) + (a2 + a3);

    if (lane >= HH && lane < HH + KK)
      keyg[((size_t)b * KK + (lane - HH)) * 257 + t] = acc + bias;
    if (lane >= HH + KK && lane < HH + 2 * KK && t >= 1)
      qg[((size_t)b * KK + (lane - HH - KK)) * 256 + (t - 1)] = acc + bias;

    if (t < TT) {
      const float cn = fmaxf(acc + gv0, 0.f);
      gv0 = gv1;
      gv1 = gvn;
      if (lane < HH) ctxg[((size_t)b * 257 + (t + 1)) * HH + lane] = cn;
      c_reg = (lane < HH) ? cn : 0.f;
    }
  }
}

// ---------------- K3: attention + output ----------------
// Block = (b, 32-t chunk), heavy chunks launched first (LPT). LDS = ct tile
// only (64 x 66 = 16.9KB). Keys/q read straight from global (L2-hot).
__global__ __launch_bounds__(256, 4) void k3_attn(
    const float* __restrict__ ctxg, const float* __restrict__ keyg,
    const float* __restrict__ qg, const float* __restrict__ W_act,
    const float* __restrict__ b_act, float* __restrict__ out) {
  __shared__ __align__(16) float ct[64 * CTS];

  const int tid = threadIdx.x;
  const int bid = blockIdx.x;
  const int chunk = 7 - (bid >> 9);  // heavy-first
  const int b = bid & 511;
  const int tbase = chunk * 32;
  const int nst = tbase + 33;  // history rows needed: s in [0, nst)
  const int ntiles = (nst + 63) >> 6;

  const int wave = tid >> 6;
  const int lane = tid & 63;

  // hoist q for this wave's 8 t's into registers (uniform loads)
  float qr[2][4][KK];
#pragma unroll
  for (int gidx = 0; gidx < 2; ++gidx)
#pragma unroll
    for (int i = 0; i < 4; ++i) {
      const int t = tbase + gidx * 16 + wave * 4 + i;
#pragma unroll
      for (int k = 0; k < KK; ++k)
        qr[gidx][i][k] = qg[((size_t)b * KK + k) * 256 + t];
    }

  float wact[AA], ba[AA];
#pragma unroll
  for (int a = 0; a < AA; ++a) wact[a] = (lane < HH) ? W_act[a * HH + lane] : 0.f;
#pragma unroll
  for (int a = 0; a < AA; ++a) ba[a] = b_act[a];

  float su[2][4], w[2][4];
#pragma unroll
  for (int gp = 0; gp < 2; ++gp)
#pragma unroll
    for (int i = 0; i < 4; ++i) {
      su[gp][i] = 0.f;
      w[gp][i] = 0.f;
    }

#pragma unroll 1
  for (int tile = 0; tile < ntiles; ++tile) {
    __syncthreads();
    {  // stage ct rows [tile*64, tile*64+64), stride CTS=66 (conflict-free)
      const int r = tid >> 2;
      const int c0 = (tid & 3) * 16;
      const int s = tile * 64 + r;
      float2* dst = reinterpret_cast<float2*>(ct + r * CTS + c0);
      const float* src = ctxg + ((size_t)b * 257 + s) * HH;
      const bool sv = (s < nst);
#pragma unroll
      for (int u = 0; u < 8; ++u) {
        const int c = c0 + u * 2;
        float2 v = make_float2(0.f, 0.f);
        if (sv && c < HH) v = *reinterpret_cast<const float2*>(src + c);
        dst[u] = v;
      }
    }
    __syncthreads();

    const int sbase = tile * 64;
    const int s = sbase + lane;
    float kv[KK];
#pragma unroll
    for (int k = 0; k < KK; ++k)
      kv[k] = keyg[((size_t)b * KK + k) * 257 + s];  // coalesced; OOB masked

#pragma unroll
    for (int gidx = 0; gidx < 2; ++gidx) {
      const int t0 = tbase + gidx * 16 + wave * 4;
      const int smax = t0 + 4 - sbase;  // largest valid sl in this tile
      if (smax < 0) continue;           // wave-uniform

      float p[4];
#pragma unroll
      for (int i = 0; i < 4; ++i) {
        float sc = qr[gidx][i][0] * kv[0];
        sc = fmaf(qr[gidx][i][1], kv[1], sc);
        sc = fmaf(qr[gidx][i][2], kv[2], sc);
        sc = fmaf(qr[gidx][i][3], kv[3], sc);
        sc = fmaf(qr[gidx][i][4], kv[4], sc);
        const bool valid = (s <= t0 + i + 1);
        p[i] = valid ? __expf(sc) : 0.f;
        su[gidx][i] += p[i];
      }

      const float* crow = ct + lane;
#pragma unroll 1
      for (int sl0 = 0; sl0 < 64; sl0 += 16) {
        if (sl0 > smax) break;
#pragma unroll
        for (int u = 0; u < 16; ++u) {
          const int sl = sl0 + u;
          const float cv = crow[sl * CTS];
#pragma unroll
          for (int i = 0; i < 4; ++i) {
            const float ps = __int_as_float(
                __builtin_amdgcn_readlane(__float_as_int(p[i]), sl));
            w[gidx][i] = fmaf(ps, cv, w[gidx][i]);
          }
        }
      }
    }
  }

  // epilogue
#pragma unroll
  for (int gidx = 0; gidx < 2; ++gidx) {
    const int t0 = tbase + gidx * 16 + wave * 4;
#pragma unroll
    for (int i = 0; i < 4; ++i) {
      float v0 = w[gidx][i] * wact[0];
      float v1 = w[gidx][i] * wact[1];
      float v2 = w[gidx][i] * wact[2];
      float v3 = w[gidx][i] * wact[3];
      float st = su[gidx][i];
#pragma unroll
      for (int d = 1; d < 64; d <<= 1) {
        v0 += __shfl_xor(v0, d, 64);
        v1 += __shfl_xor(v1, d, 64);
        v2 += __shfl_xor(v2, d, 64);
        v3 += __shfl_xor(v3, d, 64);
        st += __shfl_xor(st, d, 64);
      }
      if (lane == 0) {
        const float inv = 1.f / st;
        *reinterpret_cast<float4*>(out + (size_t)((t0 + i) * BB + b) * AA) =
            make_float4(fmaf(v0, inv, ba[0]), fmaf(v1, inv, ba[1]),
                        fmaf(v2, inv, ba[2]), fmaf(v3, inv, ba[3]));
      }
    }
  }
}

extern "C" void kernel_launch(void* const* d_in, const int* in_sizes, int n_in,
                              void* d_out, int out_size, void* d_ws,
                              size_t ws_size, hipStream_t stream) {
  const float* x = (const float*)d_in[0];
  const float* W_in = (const float*)d_in[1];
  const float* b_in = (const float*)d_in[2];
  const float* W_ctx = (const float*)d_in[3];
  const float* b_ctx = (const float*)d_in[4];
  const float* W_key = (const float*)d_in[5];
  const float* b_key = (const float*)d_in[6];
  const float* W_q = (const float*)d_in[7];
  const float* b_q = (const float*)d_in[8];
  const float* fc = (const float*)d_in[9];
  const float* W_act = (const float*)d_in[10];
  const float* b_act = (const float*)d_in[11];
  float* out = (float*)d_out;
  float* ws = (float*)d_ws;

  float* WT = ws;                                // 128*52
  float* WHT = ws + 8192;                        // 50*52
  float* g = ws + 16384;                         // 131072*52
  float* hbuf = g + (size_t)131072 * GSTRIDE;    // 131072*52
  float* ctxg = hbuf;                            // alias: hbuf dead after k1b
  float* keyg = hbuf + (size_t)131072 * GSTRIDE; // 512*5*257
  float* qg = keyg + (size_t)BB * KK * 257;      // 512*5*256

  hipLaunchKernelGGL(k0_prep, dim3(26), dim3(256), 0, stream, W_in, W_ctx, WT,
                     WHT);
  hipLaunchKernelGGL(k1a, dim3(512), dim3(256), 0, stream, x, WT, b_in, hbuf);
  hipLaunchKernelGGL(k1b, dim3(512), dim3(256), 0, stream, hbuf, WHT, b_ctx, g);
  hipLaunchKernelGGL(k2_rec, dim3(512), dim3(64), 0, stream, g, W_ctx, W_key,
                     b_key, W_q, b_q, fc, ctxg, keyg, qg);
  hipLaunchKernelGGL(k3_attn, dim3(4096), dim3(256), 0, stream, ctxg, keyg, qg,
                     W_act, b_act, out);
}

// Round 4
// 388.955 us; speedup vs baseline: 1.0021x; 1.0021x over previous
//
#include <hip/hip_runtime.h>

#define TT 256
#define BB 512
#define DD 128
#define HH 50
#define KK 5
#define AA 4
#define GSTRIDE 52
#define CTS 66  // ct LDS row stride (floats): banks (2r+c)%32 -> <=2-way, free

// ---------------- K0: weight prep ----------------
// WT   [128][52]: WT[j][h] = W_in[h][j]
// WHT  [50][52] : WHT[j][h] = W_ctx[h][50+j]   (h-part of W_ctx)
// WK2T [50][64] : WK2T[j][l] = role-row l, col j  (c/key/q fused, transposed)
// bias2[64]     : 0 / b_key / b_q by lane role
__global__ void k0_prep(const float* __restrict__ W_in,
                        const float* __restrict__ W_ctx,
                        const float* __restrict__ W_key,
                        const float* __restrict__ W_q,
                        const float* __restrict__ b_key,
                        const float* __restrict__ b_q,
                        float* __restrict__ WT, float* __restrict__ WHT,
                        float* __restrict__ WK2T, float* __restrict__ bias2) {
  int i = blockIdx.x * 256 + threadIdx.x;
  if (i < DD * 52) {
    int j = i / 52, h = i % 52;
    WT[i] = (h < HH) ? W_in[h * DD + j] : 0.f;
  }
  if (i < HH * 52) {
    int j = i / 52, h = i % 52;
    WHT[i] = (h < HH) ? W_ctx[h * (2 * HH) + HH + j] : 0.f;
  }
  if (i < HH * 64) {
    int j = i >> 6, l = i & 63;
    float v = 0.f;
    if (l < HH) v = W_ctx[l * (2 * HH) + j];
    else if (l < HH + KK) v = W_key[(l - HH) * HH + j];
    else if (l < HH + 2 * KK) v = W_q[(l - HH - KK) * HH + j];
    WK2T[i] = v;
  }
  if (i < 64) {
    float bv = 0.f;
    if (i >= HH && i < HH + KK) bv = b_key[i - HH];
    else if (i >= HH + KK && i < HH + 2 * KK) bv = b_q[i - HH - KK];
    bias2[i] = bv;
  }
}

// ---------------- K1a: h = relu(x @ W_in^T + b_in) ----------------
__global__ __launch_bounds__(256) void k1a(const float* __restrict__ x,
                                           const float* __restrict__ WT,
                                           const float* __restrict__ b_in,
                                           float* __restrict__ hbuf) {
  const int row = blockIdx.x * 256 + threadIdx.x;
  const float* __restrict__ xr = x + (size_t)row * DD;

  float hacc[HH];
#pragma unroll
  for (int h = 0; h < HH; ++h) hacc[h] = b_in[h];

#pragma unroll 1
  for (int j = 0; j < DD; j += 4) {
    const float4 xv = *reinterpret_cast<const float4*>(xr + j);
    const float* __restrict__ w0 = WT + (j + 0) * 52;
    const float* __restrict__ w1 = WT + (j + 1) * 52;
    const float* __restrict__ w2 = WT + (j + 2) * 52;
    const float* __restrict__ w3 = WT + (j + 3) * 52;
#pragma unroll
    for (int h = 0; h < HH; ++h) {
      float t0 = fmaf(xv.x, w0[h], hacc[h]);
      float t1 = fmaf(xv.y, w1[h], t0);
      float t2 = fmaf(xv.z, w2[h], t1);
      hacc[h] = fmaf(xv.w, w3[h], t2);
    }
  }

  float* __restrict__ hr = hbuf + (size_t)row * GSTRIDE;
#pragma unroll
  for (int h = 0; h < 48; h += 4) {
    *reinterpret_cast<float4*>(hr + h) =
        make_float4(fmaxf(hacc[h], 0.f), fmaxf(hacc[h + 1], 0.f),
                    fmaxf(hacc[h + 2], 0.f), fmaxf(hacc[h + 3], 0.f));
  }
  *reinterpret_cast<float2*>(hr + 48) =
      make_float2(fmaxf(hacc[48], 0.f), fmaxf(hacc[49], 0.f));
}

// ---------------- K1b: g = h @ Wh^T + b_ctx ----------------
__global__ __launch_bounds__(256) void k1b(const float* __restrict__ hbuf,
                                           const float* __restrict__ WHT,
                                           const float* __restrict__ b_ctx,
                                           float* __restrict__ g) {
  const int row = blockIdx.x * 256 + threadIdx.x;
  const float* __restrict__ hr = hbuf + (size_t)row * GSTRIDE;

  float gacc[HH];
#pragma unroll
  for (int h = 0; h < HH; ++h) gacc[h] = b_ctx[h];

#pragma unroll 1
  for (int j0 = 0; j0 < 48; j0 += 4) {
    const float4 h4 = *reinterpret_cast<const float4*>(hr + j0);
#pragma unroll
    for (int u = 0; u < 4; ++u) {
      const float hv = (u == 0) ? h4.x : (u == 1) ? h4.y : (u == 2) ? h4.z : h4.w;
      const float* __restrict__ wh = WHT + (j0 + u) * 52;
#pragma unroll
      for (int h = 0; h < HH; ++h) gacc[h] = fmaf(hv, wh[h], gacc[h]);
    }
  }
  {
    const float2 h2 = *reinterpret_cast<const float2*>(hr + 48);
    const float* __restrict__ w48 = WHT + 48 * 52;
    const float* __restrict__ w49 = WHT + 49 * 52;
#pragma unroll
    for (int h = 0; h < HH; ++h)
      gacc[h] = fmaf(h2.y, w49[h], fmaf(h2.x, w48[h], gacc[h]));
  }

  float* __restrict__ gr = g + (size_t)row * GSTRIDE;
#pragma unroll
  for (int h = 0; h < 48; h += 4) {
    *reinterpret_cast<float4*>(gr + h) =
        make_float4(gacc[h], gacc[h + 1], gacc[h + 2], gacc[h + 3]);
  }
  *reinterpret_cast<float2*>(gr + 48) = make_float2(gacc[48], gacc[49]);
}

// ---------------- K2: per-batch recurrence (512 blocks x 1 wave) -----------
// Branch-free weight init from fused WK2T -> wrow stays in VGPRs.
// c broadcast via v_readlane (no DS ops in the serial chain).
// lanes 0-49: c; 50-54: keys; 55-59: q.
__global__ __launch_bounds__(64) void k2_rec(
    const float* __restrict__ g, const float* __restrict__ WK2T,
    const float* __restrict__ bias2, const float* __restrict__ first_context,
    float* __restrict__ ctxg, float* __restrict__ keyg,
    float* __restrict__ qg) {
  const int b = blockIdx.x;
  const int lane = threadIdx.x;

  float wrow[HH];
#pragma unroll
  for (int j = 0; j < HH; ++j) wrow[j] = WK2T[j * 64 + lane];  // coalesced
  const float bias = bias2[lane];

  float c_reg = (lane < HH) ? first_context[lane] : 0.f;
  if (lane < HH) ctxg[((size_t)b * 257 + 0) * HH + lane] = c_reg;

  float gv0 = (lane < HH) ? g[((size_t)0 * BB + b) * GSTRIDE + lane] : 0.f;
  float gv1 = (lane < HH) ? g[((size_t)1 * BB + b) * GSTRIDE + lane] : 0.f;

  for (int t = 0; t <= TT; ++t) {
    float gvn = 0.f;
    if (lane < HH && (t + 2) < TT)
      gvn = g[((size_t)(t + 2) * BB + b) * GSTRIDE + lane];

    float a0 = 0.f, a1 = 0.f, a2 = 0.f, a3 = 0.f;
    const int ci = __float_as_int(c_reg);
#pragma unroll
    for (int j = 0; j < 48; j += 4) {
      a0 = fmaf(wrow[j + 0], __int_as_float(__builtin_amdgcn_readlane(ci, j + 0)), a0);
      a1 = fmaf(wrow[j + 1], __int_as_float(__builtin_amdgcn_readlane(ci, j + 1)), a1);
      a2 = fmaf(wrow[j + 2], __int_as_float(__builtin_amdgcn_readlane(ci, j + 2)), a2);
      a3 = fmaf(wrow[j + 3], __int_as_float(__builtin_amdgcn_readlane(ci, j + 3)), a3);
    }
    a0 = fmaf(wrow[48], __int_as_float(__builtin_amdgcn_readlane(ci, 48)), a0);
    a1 = fmaf(wrow[49], __int_as_float(__builtin_amdgcn_readlane(ci, 49)), a1);
    const float acc = (a0 + a1) + (a2 + a3);

    if (lane >= HH && lane < HH + KK)
      keyg[((size_t)b * KK + (lane - HH)) * 257 + t] = acc + bias;
    if (lane >= HH + KK && lane < HH + 2 * KK && t >= 1)
      qg[((size_t)b * KK + (lane - HH - KK)) * 256 + (t - 1)] = acc + bias;

    if (t < TT) {
      const float cn = fmaxf(acc + gv0, 0.f);
      gv0 = gv1;
      gv1 = gvn;
      if (lane < HH) ctxg[((size_t)b * 257 + (t + 1)) * HH + lane] = cn;
      c_reg = (lane < HH) ? cn : 0.f;
    }
  }
}

// ---------------- K3: attention + output ----------------
__global__ __launch_bounds__(256, 4) void k3_attn(
    const float* __restrict__ ctxg, const float* __restrict__ keyg,
    const float* __restrict__ qg, const float* __restrict__ W_act,
    const float* __restrict__ b_act, float* __restrict__ out) {
  __shared__ __align__(16) float ct[64 * CTS];

  const int tid = threadIdx.x;
  const int bid = blockIdx.x;
  const int chunk = 7 - (bid >> 9);  // heavy-first
  const int b = bid & 511;
  const int tbase = chunk * 32;
  const int nst = tbase + 33;  // history rows needed: s in [0, nst)
  const int ntiles = (nst + 63) >> 6;

  const int wave = tid >> 6;
  const int lane = tid & 63;

  float qr[2][4][KK];
#pragma unroll
  for (int gidx = 0; gidx < 2; ++gidx)
#pragma unroll
    for (int i = 0; i < 4; ++i) {
      const int t = tbase + gidx * 16 + wave * 4 + i;
#pragma unroll
      for (int k = 0; k < KK; ++k)
        qr[gidx][i][k] = qg[((size_t)b * KK + k) * 256 + t];
    }

  float wact[AA], ba[AA];
#pragma unroll
  for (int a = 0; a < AA; ++a) wact[a] = (lane < HH) ? W_act[a * HH + lane] : 0.f;
#pragma unroll
  for (int a = 0; a < AA; ++a) ba[a] = b_act[a];

  float su[2][4], w[2][4];
#pragma unroll
  for (int gp = 0; gp < 2; ++gp)
#pragma unroll
    for (int i = 0; i < 4; ++i) {
      su[gp][i] = 0.f;
      w[gp][i] = 0.f;
    }

#pragma unroll 1
  for (int tile = 0; tile < ntiles; ++tile) {
    __syncthreads();
    {  // stage ct rows [tile*64, tile*64+64), stride CTS=66 (conflict-free)
      const int r = tid >> 2;
      const int c0 = (tid & 3) * 16;
      const int s = tile * 64 + r;
      float2* dst = reinterpret_cast<float2*>(ct + r * CTS + c0);
      const float* src = ctxg + ((size_t)b * 257 + s) * HH;
      const bool sv = (s < nst);
#pragma unroll
      for (int u = 0; u < 8; ++u) {
        const int c = c0 + u * 2;
        float2 v = make_float2(0.f, 0.f);
        if (sv && c < HH) v = *reinterpret_cast<const float2*>(src + c);
        dst[u] = v;
      }
    }
    __syncthreads();

    const int sbase = tile * 64;
    const int s = sbase + lane;
    float kv[KK];
#pragma unroll
    for (int k = 0; k < KK; ++k)
      kv[k] = keyg[((size_t)b * KK + k) * 257 + s];

#pragma unroll
    for (int gidx = 0; gidx < 2; ++gidx) {
      const int t0 = tbase + gidx * 16 + wave * 4;
      const int smax = t0 + 4 - sbase;
      if (smax < 0) continue;  // wave-uniform

      float p[4];
#pragma unroll
      for (int i = 0; i < 4; ++i) {
        float sc = qr[gidx][i][0] * kv[0];
        sc = fmaf(qr[gidx][i][1], kv[1], sc);
        sc = fmaf(qr[gidx][i][2], kv[2], sc);
        sc = fmaf(qr[gidx][i][3], kv[3], sc);
        sc = fmaf(qr[gidx][i][4], kv[4], sc);
        const bool valid = (s <= t0 + i + 1);
        p[i] = valid ? __expf(sc) : 0.f;
        su[gidx][i] += p[i];
      }

      const float* crow = ct + lane;
#pragma unroll 1
      for (int sl0 = 0; sl0 < 64; sl0 += 16) {
        if (sl0 > smax) break;
#pragma unroll
        for (int u = 0; u < 16; ++u) {
          const int sl = sl0 + u;
          const float cv = crow[sl * CTS];
#pragma unroll
          for (int i = 0; i < 4; ++i) {
            const float ps = __int_as_float(
                __builtin_amdgcn_readlane(__float_as_int(p[i]), sl));
            w[gidx][i] = fmaf(ps, cv, w[gidx][i]);
          }
        }
      }
    }
  }

#pragma unroll
  for (int gidx = 0; gidx < 2; ++gidx) {
    const int t0 = tbase + gidx * 16 + wave * 4;
#pragma unroll
    for (int i = 0; i < 4; ++i) {
      float v0 = w[gidx][i] * wact[0];
      float v1 = w[gidx][i] * wact[1];
      float v2 = w[gidx][i] * wact[2];
      float v3 = w[gidx][i] * wact[3];
      float st = su[gidx][i];
#pragma unroll
      for (int d = 1; d < 64; d <<= 1) {
        v0 += __shfl_xor(v0, d, 64);
        v1 += __shfl_xor(v1, d, 64);
        v2 += __shfl_xor(v2, d, 64);
        v3 += __shfl_xor(v3, d, 64);
        st += __shfl_xor(st, d, 64);
      }
      if (lane == 0) {
        const float inv = 1.f / st;
        *reinterpret_cast<float4*>(out + (size_t)((t0 + i) * BB + b) * AA) =
            make_float4(fmaf(v0, inv, ba[0]), fmaf(v1, inv, ba[1]),
                        fmaf(v2, inv, ba[2]), fmaf(v3, inv, ba[3]));
      }
    }
  }
}

extern "C" void kernel_launch(void* const* d_in, const int* in_sizes, int n_in,
                              void* d_out, int out_size, void* d_ws,
                              size_t ws_size, hipStream_t stream) {
  const float* x = (const float*)d_in[0];
  const float* W_in = (const float*)d_in[1];
  const float* b_in = (const float*)d_in[2];
  const float* W_ctx = (const float*)d_in[3];
  const float* b_ctx = (const float*)d_in[4];
  const float* W_key = (const float*)d_in[5];
  const float* b_key = (const float*)d_in[6];
  const float* W_q = (const float*)d_in[7];
  const float* b_q = (const float*)d_in[8];
  const float* fc = (const float*)d_in[9];
  const float* W_act = (const float*)d_in[10];
  const float* b_act = (const float*)d_in[11];
  float* out = (float*)d_out;
  float* ws = (float*)d_ws;

  float* WT = ws;                                 // 128*52 = 6656
  float* WHT = ws + 8192;                         // 50*52  = 2600
  float* WK2T = ws + 12288;                       // 50*64  = 3200
  float* bias2 = ws + 15616;                      // 64
  float* g = ws + 16384;                          // 131072*52
  float* hbuf = g + (size_t)131072 * GSTRIDE;     // 131072*52
  float* ctxg = hbuf;                             // alias: hbuf dead after k1b
  float* keyg = hbuf + (size_t)131072 * GSTRIDE;  // 512*5*257
  float* qg = keyg + (size_t)BB * KK * 257;       // 512*5*256

  hipLaunchKernelGGL(k0_prep, dim3(26), dim3(256), 0, stream, W_in, W_ctx,
                     W_key, W_q, b_key, b_q, WT, WHT, WK2T, bias2);
  hipLaunchKernelGGL(k1a, dim3(512), dim3(256), 0, stream, x, WT, b_in, hbuf);
  hipLaunchKernelGGL(k1b, dim3(512), dim3(256), 0, stream, hbuf, WHT, b_ctx, g);
  hipLaunchKernelGGL(k2_rec, dim3(512), dim3(64), 0, stream, g, WK2T, bias2,
                     fc, ctxg, keyg, qg);
  hipLaunchKernelGGL(k3_attn, dim3(4096), dim3(256), 0, stream, ctxg, keyg, qg,
                     W_act, b_act, out);
}

// Round 5
// 356.405 us; speedup vs baseline: 1.0936x; 1.0913x over previous
//
#include <hip/hip_runtime.h>

#define TT 256
#define BB 512
#define DD 128
#define HH 50
#define KK 5
#define AA 4
#define GSTRIDE 52
#define CTS 66  // ct LDS row stride (floats): <=2-way bank aliasing (free)

#define R50(X) X(0) X(1) X(2) X(3) X(4) X(5) X(6) X(7) X(8) X(9) \
  X(10) X(11) X(12) X(13) X(14) X(15) X(16) X(17) X(18) X(19) \
  X(20) X(21) X(22) X(23) X(24) X(25) X(26) X(27) X(28) X(29) \
  X(30) X(31) X(32) X(33) X(34) X(35) X(36) X(37) X(38) X(39) \
  X(40) X(41) X(42) X(43) X(44) X(45) X(46) X(47) X(48) X(49)
#define R16(X) X(0) X(1) X(2) X(3) X(4) X(5) X(6) X(7) \
  X(8) X(9) X(10) X(11) X(12) X(13) X(14) X(15)
#define G2(X) X(A,0) X(A,1) X(A,2) X(A,3) X(B,0) X(B,1) X(B,2) X(B,3)

// ---------------- K0: weight prep ----------------
__global__ void k0_prep(const float* __restrict__ W_in,
                        const float* __restrict__ W_ctx,
                        const float* __restrict__ W_key,
                        const float* __restrict__ W_q,
                        const float* __restrict__ b_key,
                        const float* __restrict__ b_q,
                        float* __restrict__ WT, float* __restrict__ WHT,
                        float* __restrict__ WK2T, float* __restrict__ bias2) {
  int i = blockIdx.x * 256 + threadIdx.x;
  if (i < DD * 52) {
    int j = i / 52, h = i % 52;
    WT[i] = (h < HH) ? W_in[h * DD + j] : 0.f;
  }
  if (i < HH * 52) {
    int j = i / 52, h = i % 52;
    WHT[i] = (h < HH) ? W_ctx[h * (2 * HH) + HH + j] : 0.f;
  }
  if (i < HH * 64) {
    int j = i >> 6, l = i & 63;
    float v = 0.f;
    if (l < HH) v = W_ctx[l * (2 * HH) + j];
    else if (l < HH + KK) v = W_key[(l - HH) * HH + j];
    else if (l < HH + 2 * KK) v = W_q[(l - HH - KK) * HH + j];
    WK2T[i] = v;
  }
  if (i < 64) {
    float bv = 0.f;
    if (i >= HH && i < HH + KK) bv = b_key[i - HH];
    else if (i >= HH + KK && i < HH + 2 * KK) bv = b_q[i - HH - KK];
    bias2[i] = bv;
  }
}

// ---------------- K1 (fused): g = relu(x@W_in^T+b_in)@Wh^T + b_ctx --------
// All 100 accumulators are NAMED scalars -> guaranteed VGPRs (no alloca).
// Weight reads are thread-uniform -> scalar loads.
__global__ __launch_bounds__(256) void k1_fused(
    const float* __restrict__ x, const float* __restrict__ WT,
    const float* __restrict__ WHT, const float* __restrict__ b_in,
    const float* __restrict__ b_ctx, float* __restrict__ g) {
  const int row = blockIdx.x * 256 + threadIdx.x;
  const float* __restrict__ xr = x + (size_t)row * DD;

#define DECLA(h) float a##h = b_in[h];
  R50(DECLA)

#pragma unroll 1
  for (int j = 0; j < DD; j += 4) {
    const float4 xv = *reinterpret_cast<const float4*>(xr + j);
    const float* __restrict__ w0 = WT + (j + 0) * 52;
    const float* __restrict__ w1 = WT + (j + 1) * 52;
    const float* __restrict__ w2 = WT + (j + 2) * 52;
    const float* __restrict__ w3 = WT + (j + 3) * 52;
#define FMA4(h)                    \
  a##h = fmaf(xv.x, w0[h], a##h);  \
  a##h = fmaf(xv.y, w1[h], a##h);  \
  a##h = fmaf(xv.z, w2[h], a##h);  \
  a##h = fmaf(xv.w, w3[h], a##h);
    R50(FMA4)
  }

#define RELUA(h) a##h = fmaxf(a##h, 0.f);
  R50(RELUA)

#define DECLG(h) float g##h = b_ctx[h];
  R50(DECLG)

#define GH(h) g##h = fmaf(av, wh[h], g##h);
#define GJ(j, an) { const float av = an; const float* __restrict__ wh = WHT + (j) * 52; R50(GH) }
  GJ(0, a0) GJ(1, a1) GJ(2, a2) GJ(3, a3) GJ(4, a4)
  GJ(5, a5) GJ(6, a6) GJ(7, a7) GJ(8, a8) GJ(9, a9)
  GJ(10, a10) GJ(11, a11) GJ(12, a12) GJ(13, a13) GJ(14, a14)
  GJ(15, a15) GJ(16, a16) GJ(17, a17) GJ(18, a18) GJ(19, a19)
  GJ(20, a20) GJ(21, a21) GJ(22, a22) GJ(23, a23) GJ(24, a24)
  GJ(25, a25) GJ(26, a26) GJ(27, a27) GJ(28, a28) GJ(29, a29)
  GJ(30, a30) GJ(31, a31) GJ(32, a32) GJ(33, a33) GJ(34, a34)
  GJ(35, a35) GJ(36, a36) GJ(37, a37) GJ(38, a38) GJ(39, a39)
  GJ(40, a40) GJ(41, a41) GJ(42, a42) GJ(43, a43) GJ(44, a44)
  GJ(45, a45) GJ(46, a46) GJ(47, a47) GJ(48, a48) GJ(49, a49)

  float* __restrict__ gr = g + (size_t)row * GSTRIDE;
  *reinterpret_cast<float4*>(gr + 0) = make_float4(g0, g1, g2, g3);
  *reinterpret_cast<float4*>(gr + 4) = make_float4(g4, g5, g6, g7);
  *reinterpret_cast<float4*>(gr + 8) = make_float4(g8, g9, g10, g11);
  *reinterpret_cast<float4*>(gr + 12) = make_float4(g12, g13, g14, g15);
  *reinterpret_cast<float4*>(gr + 16) = make_float4(g16, g17, g18, g19);
  *reinterpret_cast<float4*>(gr + 20) = make_float4(g20, g21, g22, g23);
  *reinterpret_cast<float4*>(gr + 24) = make_float4(g24, g25, g26, g27);
  *reinterpret_cast<float4*>(gr + 28) = make_float4(g28, g29, g30, g31);
  *reinterpret_cast<float4*>(gr + 32) = make_float4(g32, g33, g34, g35);
  *reinterpret_cast<float4*>(gr + 36) = make_float4(g36, g37, g38, g39);
  *reinterpret_cast<float4*>(gr + 40) = make_float4(g40, g41, g42, g43);
  *reinterpret_cast<float4*>(gr + 44) = make_float4(g44, g45, g46, g47);
  *reinterpret_cast<float2*>(gr + 48) = make_float2(g48, g49);
}

// ---------------- K2: per-batch recurrence (512 blocks x 1 wave) -----------
// Named weight scalars w0..w49 (VGPRs). c broadcast via v_readlane.
// lanes 0-49: c; 50-54: keys; 55-59: q. 3-deep g prefetch.
__global__ __launch_bounds__(64) void k2_rec(
    const float* __restrict__ g, const float* __restrict__ WK2T,
    const float* __restrict__ bias2, const float* __restrict__ first_context,
    float* __restrict__ ctxg, float* __restrict__ keyg,
    float* __restrict__ qg) {
  const int b = blockIdx.x;
  const int lane = threadIdx.x;

#define WDECL(j) const float w##j = WK2T[(j) * 64 + lane];
  R50(WDECL)
  const float bias = bias2[lane];

  float c_reg = (lane < HH) ? first_context[lane] : 0.f;
  if (lane < HH) ctxg[((size_t)b * 257 + 0) * HH + lane] = c_reg;

  float gv0 = (lane < HH) ? g[((size_t)0 * BB + b) * GSTRIDE + lane] : 0.f;
  float gv1 = (lane < HH) ? g[((size_t)1 * BB + b) * GSTRIDE + lane] : 0.f;
  float gv2 = (lane < HH) ? g[((size_t)2 * BB + b) * GSTRIDE + lane] : 0.f;

#define RLC(j) __int_as_float(__builtin_amdgcn_readlane(ci, j))
#define D4(j0, j1, j2, j3)            \
  acc0 = fmaf(w##j0, RLC(j0), acc0);  \
  acc1 = fmaf(w##j1, RLC(j1), acc1);  \
  acc2 = fmaf(w##j2, RLC(j2), acc2);  \
  acc3 = fmaf(w##j3, RLC(j3), acc3);

  for (int t = 0; t <= TT; ++t) {
    float gvn = 0.f;
    if (lane < HH && (t + 3) < TT)
      gvn = g[((size_t)(t + 3) * BB + b) * GSTRIDE + lane];

    const int ci = __float_as_int(c_reg);
    float acc0 = 0.f, acc1 = 0.f, acc2 = 0.f, acc3 = 0.f;
    D4(0, 1, 2, 3) D4(4, 5, 6, 7) D4(8, 9, 10, 11) D4(12, 13, 14, 15)
    D4(16, 17, 18, 19) D4(20, 21, 22, 23) D4(24, 25, 26, 27)
    D4(28, 29, 30, 31) D4(32, 33, 34, 35) D4(36, 37, 38, 39)
    D4(40, 41, 42, 43) D4(44, 45, 46, 47)
    acc0 = fmaf(w48, RLC(48), acc0);
    acc1 = fmaf(w49, RLC(49), acc1);
    const float acc = (acc0 + acc1) + (acc2 + acc3);

    if (lane >= HH && lane < HH + KK)
      keyg[((size_t)b * KK + (lane - HH)) * 257 + t] = acc + bias;
    if (lane >= HH + KK && lane < HH + 2 * KK && t >= 1)
      qg[((size_t)b * KK + (lane - HH - KK)) * 256 + (t - 1)] = acc + bias;

    if (t < TT) {
      const float cn = fmaxf(acc + gv0, 0.f);
      gv0 = gv1;
      gv1 = gv2;
      gv2 = gvn;
      if (lane < HH) ctxg[((size_t)b * 257 + (t + 1)) * HH + lane] = cn;
      c_reg = (lane < HH) ? cn : 0.f;
    }
  }
}

// ---------------- K3: attention + output ----------------
// Block = (b, 32-t chunk), heavy-first. All per-t state in NAMED scalars.
// Each wave owns 8 t's (A:tbase+w*4+i, B:+16). Combined 8-t PV pass:
// per s-slot = 1 ds_read + 8 readlane + 8 fma.
__global__ __launch_bounds__(256, 4) void k3_attn(
    const float* __restrict__ ctxg, const float* __restrict__ keyg,
    const float* __restrict__ qg, const float* __restrict__ W_act,
    const float* __restrict__ b_act, float* __restrict__ out) {
  __shared__ __align__(16) float ct[64 * CTS];

  const int tid = threadIdx.x;
  const int bid = blockIdx.x;
  const int chunk = 7 - (bid >> 9);  // heavy-first
  const int b = bid & 511;
  const int tbase = chunk * 32;
  const int nst = tbase + 33;
  const int ntiles = (nst + 63) >> 6;
  const int wave = tid >> 6;
  const int lane = tid & 63;
  const int qb0 = b * (KK * 256);
  const int kb0 = b * (KK * 257);

#define QL(gn, i, toff)                                  \
  const int t##gn##i = tbase + (toff) + wave * 4 + (i);  \
  const float q##gn##i##_0 = qg[qb0 + 0 * 256 + t##gn##i]; \
  const float q##gn##i##_1 = qg[qb0 + 1 * 256 + t##gn##i]; \
  const float q##gn##i##_2 = qg[qb0 + 2 * 256 + t##gn##i]; \
  const float q##gn##i##_3 = qg[qb0 + 3 * 256 + t##gn##i]; \
  const float q##gn##i##_4 = qg[qb0 + 4 * 256 + t##gn##i];
  QL(A, 0, 0) QL(A, 1, 0) QL(A, 2, 0) QL(A, 3, 0)
  QL(B, 0, 16) QL(B, 1, 16) QL(B, 2, 16) QL(B, 3, 16)

#define ZSO(gn, i) float s_##gn##i = 0.f, o_##gn##i = 0.f;
  G2(ZSO)

  const float wa0 = (lane < HH) ? W_act[0 * HH + lane] : 0.f;
  const float wa1 = (lane < HH) ? W_act[1 * HH + lane] : 0.f;
  const float wa2 = (lane < HH) ? W_act[2 * HH + lane] : 0.f;
  const float wa3 = (lane < HH) ? W_act[3 * HH + lane] : 0.f;
  const float ba0 = b_act[0], ba1 = b_act[1], ba2 = b_act[2], ba3 = b_act[3];

#pragma unroll 1
  for (int tile = 0; tile < ntiles; ++tile) {
    __syncthreads();
    {  // stage ct rows [tile*64, tile*64+64), stride CTS (conflict-free)
      const int r = tid >> 2;
      const int c0 = (tid & 3) * 16;
      const int srow = tile * 64 + r;
      float2* dst = reinterpret_cast<float2*>(ct + r * CTS + c0);
      const float* src = ctxg + ((size_t)b * 257 + srow) * HH;
      const bool sv = (srow < nst);
#pragma unroll
      for (int u = 0; u < 8; ++u) {
        const int c = c0 + u * 2;
        float2 v = make_float2(0.f, 0.f);
        if (sv && c < HH) v = *reinterpret_cast<const float2*>(src + c);
        dst[u] = v;
      }
    }
    __syncthreads();

    const int sbase = tile * 64;
    const int smax = tB3 + 1 - sbase;  // largest valid s-slot for this wave
    if (smax < 0) continue;            // wave-uniform; barriers still met

    const int s = sbase + lane;
    const float kv0 = keyg[kb0 + 0 * 257 + s];
    const float kv1 = keyg[kb0 + 1 * 257 + s];
    const float kv2 = keyg[kb0 + 2 * 257 + s];
    const float kv3 = keyg[kb0 + 3 * 257 + s];
    const float kv4 = keyg[kb0 + 4 * 257 + s];

#define SCORE(gn, i)                              \
  float p_##gn##i;                                \
  {                                               \
    float sc = q##gn##i##_0 * kv0;                \
    sc = fmaf(q##gn##i##_1, kv1, sc);             \
    sc = fmaf(q##gn##i##_2, kv2, sc);             \
    sc = fmaf(q##gn##i##_3, kv3, sc);             \
    sc = fmaf(q##gn##i##_4, kv4, sc);             \
    p_##gn##i = (s <= t##gn##i + 1) ? __expf(sc) : 0.f; \
    s_##gn##i += p_##gn##i;                       \
  }
    G2(SCORE)

    const float* crow = ct + lane;
#define PVB(gn, i, u)                                                        \
  o_##gn##i = fmaf(__int_as_float(__builtin_amdgcn_readlane(                 \
                       __float_as_int(p_##gn##i), sl0 + (u))),               \
                   cv, o_##gn##i);
#define PVSL(u)                                      \
  {                                                  \
    const float cv = crow[(sl0 + (u)) * CTS];        \
    PVB(A, 0, u) PVB(A, 1, u) PVB(A, 2, u) PVB(A, 3, u) \
    PVB(B, 0, u) PVB(B, 1, u) PVB(B, 2, u) PVB(B, 3, u) \
  }
#pragma unroll 1
    for (int sl0 = 0; sl0 < 64; sl0 += 16) {
      if (sl0 > smax) break;
      R16(PVSL)
    }
  }

#define RED5(d)                  \
  v0 += __shfl_xor(v0, d, 64);   \
  v1 += __shfl_xor(v1, d, 64);   \
  v2 += __shfl_xor(v2, d, 64);   \
  v3 += __shfl_xor(v3, d, 64);   \
  st += __shfl_xor(st, d, 64);
#define EPI(gn, i)                                                   \
  {                                                                  \
    float v0 = o_##gn##i * wa0, v1 = o_##gn##i * wa1;                \
    float v2 = o_##gn##i * wa2, v3 = o_##gn##i * wa3;                \
    float st = s_##gn##i;                                            \
    RED5(1) RED5(2) RED5(4) RED5(8) RED5(16) RED5(32)                \
    if (lane == 0) {                                                 \
      const float inv = 1.f / st;                                    \
      *reinterpret_cast<float4*>(out +                               \
          (size_t)((t##gn##i) * BB + b) * AA) =                      \
          make_float4(fmaf(v0, inv, ba0), fmaf(v1, inv, ba1),        \
                      fmaf(v2, inv, ba2), fmaf(v3, inv, ba3));       \
    }                                                                \
  }
  G2(EPI)
}

extern "C" void kernel_launch(void* const* d_in, const int* in_sizes, int n_in,
                              void* d_out, int out_size, void* d_ws,
                              size_t ws_size, hipStream_t stream) {
  const float* x = (const float*)d_in[0];
  const float* W_in = (const float*)d_in[1];
  const float* b_in = (const float*)d_in[2];
  const float* W_ctx = (const float*)d_in[3];
  const float* b_ctx = (const float*)d_in[4];
  const float* W_key = (const float*)d_in[5];
  const float* b_key = (const float*)d_in[6];
  const float* W_q = (const float*)d_in[7];
  const float* b_q = (const float*)d_in[8];
  const float* fc = (const float*)d_in[9];
  const float* W_act = (const float*)d_in[10];
  const float* b_act = (const float*)d_in[11];
  float* out = (float*)d_out;
  float* ws = (float*)d_ws;

  float* WT = ws;                                 // 128*52
  float* WHT = ws + 8192;                         // 50*52
  float* WK2T = ws + 12288;                       // 50*64
  float* bias2 = ws + 15616;                      // 64
  float* g = ws + 16384;                          // 131072*52
  float* ctxg = g + (size_t)131072 * GSTRIDE;     // 512*257*50
  float* keyg = ctxg + (size_t)BB * 257 * HH;     // 512*5*257
  float* qg = keyg + (size_t)BB * KK * 257;       // 512*5*256

  hipLaunchKernelGGL(k0_prep, dim3(26), dim3(256), 0, stream, W_in, W_ctx,
                     W_key, W_q, b_key, b_q, WT, WHT, WK2T, bias2);
  hipLaunchKernelGGL(k1_fused, dim3(512), dim3(256), 0, stream, x, WT, WHT,
                     b_in, b_ctx, g);
  hipLaunchKernelGGL(k2_rec, dim3(512), dim3(64), 0, stream, g, WK2T, bias2,
                     fc, ctxg, keyg, qg);
  hipLaunchKernelGGL(k3_attn, dim3(4096), dim3(256), 0, stream, ctxg, keyg, qg,
                     W_act, b_act, out);
}

// Round 6
// 341.734 us; speedup vs baseline: 1.1406x; 1.0429x over previous
//
#include <hip/hip_runtime.h>

#define TT 256
#define BB 512
#define DD 128
#define HH 50
#define KK 5
#define AA 4
#define GSTRIDE 52
#define CTS 66  // ct LDS row stride (floats): <=2-way bank aliasing (free)

#define R50(X) X(0) X(1) X(2) X(3) X(4) X(5) X(6) X(7) X(8) X(9) \
  X(10) X(11) X(12) X(13) X(14) X(15) X(16) X(17) X(18) X(19) \
  X(20) X(21) X(22) X(23) X(24) X(25) X(26) X(27) X(28) X(29) \
  X(30) X(31) X(32) X(33) X(34) X(35) X(36) X(37) X(38) X(39) \
  X(40) X(41) X(42) X(43) X(44) X(45) X(46) X(47) X(48) X(49)
#define R16(X) X(0) X(1) X(2) X(3) X(4) X(5) X(6) X(7) \
  X(8) X(9) X(10) X(11) X(12) X(13) X(14) X(15)
#define G2(X) X(A,0) X(A,1) X(A,2) X(A,3) X(B,0) X(B,1) X(B,2) X(B,3)

// ---------------- K0: weight prep ----------------
__global__ void k0_prep(const float* __restrict__ W_in,
                        const float* __restrict__ W_ctx,
                        const float* __restrict__ W_key,
                        const float* __restrict__ W_q,
                        const float* __restrict__ b_key,
                        const float* __restrict__ b_q,
                        float* __restrict__ WT, float* __restrict__ WHT,
                        float* __restrict__ WK2T, float* __restrict__ bias2) {
  int i = blockIdx.x * 256 + threadIdx.x;
  if (i < DD * 52) {
    int j = i / 52, h = i % 52;
    WT[i] = (h < HH) ? W_in[h * DD + j] : 0.f;
  }
  if (i < HH * 52) {
    int j = i / 52, h = i % 52;
    WHT[i] = (h < HH) ? W_ctx[h * (2 * HH) + HH + j] : 0.f;
  }
  if (i < HH * 64) {
    int j = i >> 6, l = i & 63;
    float v = 0.f;
    if (l < HH) v = W_ctx[l * (2 * HH) + j];
    else if (l < HH + KK) v = W_key[(l - HH) * HH + j];
    else if (l < HH + 2 * KK) v = W_q[(l - HH - KK) * HH + j];
    WK2T[i] = v;
  }
  if (i < 64) {
    float bv = 0.f;
    if (i >= HH && i < HH + KK) bv = b_key[i - HH];
    else if (i >= HH + KK && i < HH + 2 * KK) bv = b_q[i - HH - KK];
    bias2[i] = bv;
  }
}

// ---------------- K1 (fused): g = relu(x@W_in^T+b_in)@Wh^T + b_ctx --------
// (256,2): VGPR budget 256 so the 100 named accumulators stay resident.
__global__ __launch_bounds__(256, 2) void k1_fused(
    const float* __restrict__ x, const float* __restrict__ WT,
    const float* __restrict__ WHT, const float* __restrict__ b_in,
    const float* __restrict__ b_ctx, float* __restrict__ g) {
  const int row = blockIdx.x * 256 + threadIdx.x;
  const float* __restrict__ xr = x + (size_t)row * DD;

#define DECLA(h) float a##h = b_in[h];
  R50(DECLA)

#pragma unroll 1
  for (int j = 0; j < DD; j += 4) {
    const float4 xv = *reinterpret_cast<const float4*>(xr + j);
    const float* __restrict__ w0 = WT + (j + 0) * 52;
    const float* __restrict__ w1 = WT + (j + 1) * 52;
    const float* __restrict__ w2 = WT + (j + 2) * 52;
    const float* __restrict__ w3 = WT + (j + 3) * 52;
#define FMA4(h)                    \
  a##h = fmaf(xv.x, w0[h], a##h);  \
  a##h = fmaf(xv.y, w1[h], a##h);  \
  a##h = fmaf(xv.z, w2[h], a##h);  \
  a##h = fmaf(xv.w, w3[h], a##h);
    R50(FMA4)
  }

#define RELUA(h) a##h = fmaxf(a##h, 0.f);
  R50(RELUA)

#define DECLG(h) float g##h = b_ctx[h];
  R50(DECLG)

#define GH(h) g##h = fmaf(av, wh[h], g##h);
#define GJ(j, an) { const float av = an; const float* __restrict__ wh = WHT + (j) * 52; R50(GH) }
  GJ(0, a0) GJ(1, a1) GJ(2, a2) GJ(3, a3) GJ(4, a4)
  GJ(5, a5) GJ(6, a6) GJ(7, a7) GJ(8, a8) GJ(9, a9)
  GJ(10, a10) GJ(11, a11) GJ(12, a12) GJ(13, a13) GJ(14, a14)
  GJ(15, a15) GJ(16, a16) GJ(17, a17) GJ(18, a18) GJ(19, a19)
  GJ(20, a20) GJ(21, a21) GJ(22, a22) GJ(23, a23) GJ(24, a24)
  GJ(25, a25) GJ(26, a26) GJ(27, a27) GJ(28, a28) GJ(29, a29)
  GJ(30, a30) GJ(31, a31) GJ(32, a32) GJ(33, a33) GJ(34, a34)
  GJ(35, a35) GJ(36, a36) GJ(37, a37) GJ(38, a38) GJ(39, a39)
  GJ(40, a40) GJ(41, a41) GJ(42, a42) GJ(43, a43) GJ(44, a44)
  GJ(45, a45) GJ(46, a46) GJ(47, a47) GJ(48, a48) GJ(49, a49)

  float* __restrict__ gr = g + (size_t)row * GSTRIDE;
  *reinterpret_cast<float4*>(gr + 0) = make_float4(g0, g1, g2, g3);
  *reinterpret_cast<float4*>(gr + 4) = make_float4(g4, g5, g6, g7);
  *reinterpret_cast<float4*>(gr + 8) = make_float4(g8, g9, g10, g11);
  *reinterpret_cast<float4*>(gr + 12) = make_float4(g12, g13, g14, g15);
  *reinterpret_cast<float4*>(gr + 16) = make_float4(g16, g17, g18, g19);
  *reinterpret_cast<float4*>(gr + 20) = make_float4(g20, g21, g22, g23);
  *reinterpret_cast<float4*>(gr + 24) = make_float4(g24, g25, g26, g27);
  *reinterpret_cast<float4*>(gr + 28) = make_float4(g28, g29, g30, g31);
  *reinterpret_cast<float4*>(gr + 32) = make_float4(g32, g33, g34, g35);
  *reinterpret_cast<float4*>(gr + 36) = make_float4(g36, g37, g38, g39);
  *reinterpret_cast<float4*>(gr + 40) = make_float4(g40, g41, g42, g43);
  *reinterpret_cast<float4*>(gr + 44) = make_float4(g44, g45, g46, g47);
  *reinterpret_cast<float2*>(gr + 48) = make_float2(g48, g49);
}

// ---------------- K2: per-batch recurrence (512 blocks x 1 wave) -----------
// (64,1): VGPR budget 512. Weights PINNED via opaque asm so the scheduler
// cannot rematerialize the loads inside the loop. c broadcast via readlane.
// lanes 0-49: c; 50-54: keys; 55-59: q.
__global__ __launch_bounds__(64, 1) void k2_rec(
    const float* __restrict__ g, const float* __restrict__ WK2T,
    const float* __restrict__ bias2, const float* __restrict__ first_context,
    float* __restrict__ ctxg, float* __restrict__ keyg,
    float* __restrict__ qg) {
  const int b = blockIdx.x;
  const int lane = threadIdx.x;

#define WDECL(j)                            \
  float w##j = WK2T[(j) * 64 + lane];       \
  asm volatile("" : "+v"(w##j));
  R50(WDECL)
  const float bias = bias2[lane];

  float c_reg = (lane < HH) ? first_context[lane] : 0.f;
  if (lane < HH) ctxg[((size_t)b * 257 + 0) * HH + lane] = c_reg;

  float gvA = (lane < HH) ? g[((size_t)0 * BB + b) * GSTRIDE + lane] : 0.f;
  float gvB = (lane < HH) ? g[((size_t)1 * BB + b) * GSTRIDE + lane] : 0.f;
  float gvC = (lane < HH) ? g[((size_t)2 * BB + b) * GSTRIDE + lane] : 0.f;

#define RLC(j) __int_as_float(__builtin_amdgcn_readlane(ci, j))
#define D4(j0, j1, j2, j3)            \
  acc0 = fmaf(w##j0, RLC(j0), acc0);  \
  acc1 = fmaf(w##j1, RLC(j1), acc1);  \
  acc2 = fmaf(w##j2, RLC(j2), acc2);  \
  acc3 = fmaf(w##j3, RLC(j3), acc3);
#define DOT50                                                          \
  float acc0 = 0.f, acc1 = 0.f, acc2 = 0.f, acc3 = 0.f;                \
  D4(0, 1, 2, 3) D4(4, 5, 6, 7) D4(8, 9, 10, 11) D4(12, 13, 14, 15)   \
  D4(16, 17, 18, 19) D4(20, 21, 22, 23) D4(24, 25, 26, 27)            \
  D4(28, 29, 30, 31) D4(32, 33, 34, 35) D4(36, 37, 38, 39)            \
  D4(40, 41, 42, 43) D4(44, 45, 46, 47)                               \
  acc0 = fmaf(w48, RLC(48), acc0);                                    \
  acc1 = fmaf(w49, RLC(49), acc1);                                    \
  const float acc = (acc0 + acc1) + (acc2 + acc3);

#pragma unroll 3
  for (int t = 0; t < TT; ++t) {
    float gvn = 0.f;
    if (lane < HH && (t + 3) < TT)
      gvn = g[((size_t)(t + 3) * BB + b) * GSTRIDE + lane];

    const int ci = __float_as_int(c_reg);
    DOT50

    if (lane >= HH && lane < HH + KK)
      keyg[((size_t)b * KK + (lane - HH)) * 257 + t] = acc + bias;
    if (lane >= HH + KK && lane < HH + 2 * KK && t >= 1)
      qg[((size_t)b * KK + (lane - HH - KK)) * 256 + (t - 1)] = acc + bias;

    const float cn = fmaxf(acc + gvA, 0.f);
    gvA = gvB;
    gvB = gvC;
    gvC = gvn;
    if (lane < HH) ctxg[((size_t)b * 257 + (t + 1)) * HH + lane] = cn;
    c_reg = cn;  // lanes >= 50 never read back (readlane 0..49 only)
  }

  {  // tail t = TT: key[TT] and q[TT-1]
    const int ci = __float_as_int(c_reg);
    DOT50
    if (lane >= HH && lane < HH + KK)
      keyg[((size_t)b * KK + (lane - HH)) * 257 + TT] = acc + bias;
    if (lane >= HH + KK && lane < HH + 2 * KK)
      qg[((size_t)b * KK + (lane - HH - KK)) * 256 + (TT - 1)] = acc + bias;
  }
}

// ---------------- K3: attention + output ----------------
// Block = (b, 32-t chunk), heavy-first. q values pinned resident.
__global__ __launch_bounds__(256, 4) void k3_attn(
    const float* __restrict__ ctxg, const float* __restrict__ keyg,
    const float* __restrict__ qg, const float* __restrict__ W_act,
    const float* __restrict__ b_act, float* __restrict__ out) {
  __shared__ __align__(16) float ct[64 * CTS];

  const int tid = threadIdx.x;
  const int bid = blockIdx.x;
  const int chunk = 7 - (bid >> 9);  // heavy-first
  const int b = bid & 511;
  const int tbase = chunk * 32;
  const int nst = tbase + 33;
  const int ntiles = (nst + 63) >> 6;
  const int wave = tid >> 6;
  const int lane = tid & 63;
  const int qb0 = b * (KK * 256);
  const int kb0 = b * (KK * 257);

#define QL(gn, i, toff)                                  \
  const int t##gn##i = tbase + (toff) + wave * 4 + (i);  \
  float q##gn##i##_0 = qg[qb0 + 0 * 256 + t##gn##i];     \
  float q##gn##i##_1 = qg[qb0 + 1 * 256 + t##gn##i];     \
  float q##gn##i##_2 = qg[qb0 + 2 * 256 + t##gn##i];     \
  float q##gn##i##_3 = qg[qb0 + 3 * 256 + t##gn##i];     \
  float q##gn##i##_4 = qg[qb0 + 4 * 256 + t##gn##i];     \
  asm volatile("" : "+v"(q##gn##i##_0), "+v"(q##gn##i##_1), \
                    "+v"(q##gn##i##_2), "+v"(q##gn##i##_3), \
                    "+v"(q##gn##i##_4));
  QL(A, 0, 0) QL(A, 1, 0) QL(A, 2, 0) QL(A, 3, 0)
  QL(B, 0, 16) QL(B, 1, 16) QL(B, 2, 16) QL(B, 3, 16)

#define ZSO(gn, i) float s_##gn##i = 0.f, o_##gn##i = 0.f;
  G2(ZSO)

  const float wa0 = (lane < HH) ? W_act[0 * HH + lane] : 0.f;
  const float wa1 = (lane < HH) ? W_act[1 * HH + lane] : 0.f;
  const float wa2 = (lane < HH) ? W_act[2 * HH + lane] : 0.f;
  const float wa3 = (lane < HH) ? W_act[3 * HH + lane] : 0.f;
  const float ba0 = b_act[0], ba1 = b_act[1], ba2 = b_act[2], ba3 = b_act[3];

#pragma unroll 1
  for (int tile = 0; tile < ntiles; ++tile) {
    __syncthreads();
    {  // stage ct rows [tile*64, tile*64+64), stride CTS (conflict-free)
      const int r = tid >> 2;
      const int c0 = (tid & 3) * 16;
      const int srow = tile * 64 + r;
      float2* dst = reinterpret_cast<float2*>(ct + r * CTS + c0);
      const float* src = ctxg + ((size_t)b * 257 + srow) * HH;
      const bool sv = (srow < nst);
#pragma unroll
      for (int u = 0; u < 8; ++u) {
        const int c = c0 + u * 2;
        float2 v = make_float2(0.f, 0.f);
        if (sv && c < HH) v = *reinterpret_cast<const float2*>(src + c);
        dst[u] = v;
      }
    }
    __syncthreads();

    const int sbase = tile * 64;
    const int smax = tB3 + 1 - sbase;  // largest valid s-slot for this wave
    if (smax < 0) continue;            // wave-uniform; barriers still met

    const int s = sbase + lane;
    const float kv0 = keyg[kb0 + 0 * 257 + s];
    const float kv1 = keyg[kb0 + 1 * 257 + s];
    const float kv2 = keyg[kb0 + 2 * 257 + s];
    const float kv3 = keyg[kb0 + 3 * 257 + s];
    const float kv4 = keyg[kb0 + 4 * 257 + s];

#define SCORE(gn, i)                              \
  float p_##gn##i;                                \
  {                                               \
    float sc = q##gn##i##_0 * kv0;                \
    sc = fmaf(q##gn##i##_1, kv1, sc);             \
    sc = fmaf(q##gn##i##_2, kv2, sc);             \
    sc = fmaf(q##gn##i##_3, kv3, sc);             \
    sc = fmaf(q##gn##i##_4, kv4, sc);             \
    p_##gn##i = (s <= t##gn##i + 1) ? __expf(sc) : 0.f; \
    s_##gn##i += p_##gn##i;                       \
  }
    G2(SCORE)

    const float* crow = ct + lane;
#define PVB(gn, i, u)                                                        \
  o_##gn##i = fmaf(__int_as_float(__builtin_amdgcn_readlane(                 \
                       __float_as_int(p_##gn##i), sl0 + (u))),               \
                   cv, o_##gn##i);
#define PVSL(u)                                      \
  {                                                  \
    const float cv = crow[(sl0 + (u)) * CTS];        \
    PVB(A, 0, u) PVB(A, 1, u) PVB(A, 2, u) PVB(A, 3, u) \
    PVB(B, 0, u) PVB(B, 1, u) PVB(B, 2, u) PVB(B, 3, u) \
  }
#pragma unroll 1
    for (int sl0 = 0; sl0 < 64; sl0 += 16) {
      if (sl0 > smax) break;
      R16(PVSL)
    }
  }

#define RED5(d)                  \
  v0 += __shfl_xor(v0, d, 64);   \
  v1 += __shfl_xor(v1, d, 64);   \
  v2 += __shfl_xor(v2, d, 64);   \
  v3 += __shfl_xor(v3, d, 64);   \
  st += __shfl_xor(st, d, 64);
#define EPI(gn, i)                                                   \
  {                                                                  \
    float v0 = o_##gn##i * wa0, v1 = o_##gn##i * wa1;                \
    float v2 = o_##gn##i * wa2, v3 = o_##gn##i * wa3;                \
    float st = s_##gn##i;                                            \
    RED5(1) RED5(2) RED5(4) RED5(8) RED5(16) RED5(32)                \
    if (lane == 0) {                                                 \
      const float inv = 1.f / st;                                    \
      *reinterpret_cast<float4*>(out +                               \
          (size_t)((t##gn##i) * BB + b) * AA) =                      \
          make_float4(fmaf(v0, inv, ba0), fmaf(v1, inv, ba1),        \
                      fmaf(v2, inv, ba2), fmaf(v3, inv, ba3));       \
    }                                                                \
  }
  G2(EPI)
}

extern "C" void kernel_launch(void* const* d_in, const int* in_sizes, int n_in,
                              void* d_out, int out_size, void* d_ws,
                              size_t ws_size, hipStream_t stream) {
  const float* x = (const float*)d_in[0];
  const float* W_in = (const float*)d_in[1];
  const float* b_in = (const float*)d_in[2];
  const float* W_ctx = (const float*)d_in[3];
  const float* b_ctx = (const float*)d_in[4];
  const float* W_key = (const float*)d_in[5];
  const float* b_key = (const float*)d_in[6];
  const float* W_q = (const float*)d_in[7];
  const float* b_q = (const float*)d_in[8];
  const float* fc = (const float*)d_in[9];
  const float* W_act = (const float*)d_in[10];
  const float* b_act = (const float*)d_in[11];
  float* out = (float*)d_out;
  float* ws = (float*)d_ws;

  float* WT = ws;                                 // 128*52
  float* WHT = ws + 8192;                         // 50*52
  float* WK2T = ws + 12288;                       // 50*64
  float* bias2 = ws + 15616;                      // 64
  float* g = ws + 16384;                          // 131072*52
  float* ctxg = g + (size_t)131072 * GSTRIDE;     // 512*257*50
  float* keyg = ctxg + (size_t)BB * 257 * HH;     // 512*5*257
  float* qg = keyg + (size_t)BB * KK * 257;       // 512*5*256

  hipLaunchKernelGGL(k0_prep, dim3(26), dim3(256), 0, stream, W_in, W_ctx,
                     W_key, W_q, b_key, b_q, WT, WHT, WK2T, bias2);
  hipLaunchKernelGGL(k1_fused, dim3(512), dim3(256), 0, stream, x, WT, WHT,
                     b_in, b_ctx, g);
  hipLaunchKernelGGL(k2_rec, dim3(512), dim3(64), 0, stream, g, WK2T, bias2,
                     fc, ctxg, keyg, qg);
  hipLaunchKernelGGL(k3_attn, dim3(4096), dim3(256), 0, stream, ctxg, keyg, qg,
                     W_act, b_act, out);
}

// Round 7
// 326.339 us; speedup vs baseline: 1.1944x; 1.0472x over previous
//
#include <hip/hip_runtime.h>

#define TT 256
#define BB 512
#define DD 128
#define HH 50
#define KK 5
#define AA 4
#define GSTRIDE 52
#define CTS 66  // ct LDS row stride (floats): <=2-way bank aliasing (free)

#define R50(X) X(0) X(1) X(2) X(3) X(4) X(5) X(6) X(7) X(8) X(9) \
  X(10) X(11) X(12) X(13) X(14) X(15) X(16) X(17) X(18) X(19) \
  X(20) X(21) X(22) X(23) X(24) X(25) X(26) X(27) X(28) X(29) \
  X(30) X(31) X(32) X(33) X(34) X(35) X(36) X(37) X(38) X(39) \
  X(40) X(41) X(42) X(43) X(44) X(45) X(46) X(47) X(48) X(49)
#define R16(X) X(0) X(1) X(2) X(3) X(4) X(5) X(6) X(7) \
  X(8) X(9) X(10) X(11) X(12) X(13) X(14) X(15)
#define G2(X) X(A,0) X(A,1) X(A,2) X(A,3) X(B,0) X(B,1) X(B,2) X(B,3)

// ---------------- K0: weight prep ----------------
__global__ void k0_prep(const float* __restrict__ W_in,
                        const float* __restrict__ W_ctx,
                        const float* __restrict__ W_key,
                        const float* __restrict__ W_q,
                        const float* __restrict__ b_key,
                        const float* __restrict__ b_q,
                        float* __restrict__ WT, float* __restrict__ WHT,
                        float* __restrict__ WK2T, float* __restrict__ bias2) {
  int i = blockIdx.x * 256 + threadIdx.x;
  if (i < DD * 52) {
    int j = i / 52, h = i % 52;
    WT[i] = (h < HH) ? W_in[h * DD + j] : 0.f;
  }
  if (i < HH * 52) {
    int j = i / 52, h = i % 52;
    WHT[i] = (h < HH) ? W_ctx[h * (2 * HH) + HH + j] : 0.f;
  }
  if (i < HH * 64) {
    int j = i >> 6, l = i & 63;
    float v = 0.f;
    if (l < HH) v = W_ctx[l * (2 * HH) + j];
    else if (l < HH + KK) v = W_key[(l - HH) * HH + j];
    else if (l < HH + 2 * KK) v = W_q[(l - HH - KK) * HH + j];
    WK2T[i] = v;
  }
  if (i < 64) {
    float bv = 0.f;
    if (i >= HH && i < HH + KK) bv = b_key[i - HH];
    else if (i >= HH + KK && i < HH + 2 * KK) bv = b_q[i - HH - KK];
    bias2[i] = bv;
  }
}

// ---------------- K1 (fused): g = relu(x@W_in^T+b_in)@Wh^T + b_ctx --------
// x staged through LDS in 16-col tiles: global float4 loads are
// 16-consecutive-rows per wave (fully used 64B lines); compute reads LDS
// at stride 17 (<=2-way, free). 100 named accumulators.
__global__ __launch_bounds__(256, 2) void k1_fused(
    const float* __restrict__ x, const float* __restrict__ WT,
    const float* __restrict__ WHT, const float* __restrict__ b_in,
    const float* __restrict__ b_ctx, float* __restrict__ g) {
  __shared__ float xs[256 * 17];
  const int tid = threadIdx.x;
  const float* __restrict__ xblk = x + (size_t)blockIdx.x * 256 * DD;

#define DECLA(h) float a##h = b_in[h];
  R50(DECLA)

#pragma unroll 1
  for (int jb = 0; jb < 8; ++jb) {
    __syncthreads();
#pragma unroll
    for (int u = 0; u < 4; ++u) {
      const int f = tid + u * 256;  // float4 id in [0,1024)
      const int r = f >> 2, c4 = f & 3;
      const float4 v = *reinterpret_cast<const float4*>(
          xblk + (size_t)r * DD + jb * 16 + c4 * 4);
      float* d = &xs[r * 17 + c4 * 4];
      d[0] = v.x; d[1] = v.y; d[2] = v.z; d[3] = v.w;
    }
    __syncthreads();
    const float* __restrict__ xrow = &xs[tid * 17];
#pragma unroll
    for (int cc = 0; cc < 16; cc += 4) {
      const int j = jb * 16 + cc;
      const float xv0 = xrow[cc + 0];
      const float xv1 = xrow[cc + 1];
      const float xv2 = xrow[cc + 2];
      const float xv3 = xrow[cc + 3];
      const float* __restrict__ w0 = WT + (j + 0) * 52;
      const float* __restrict__ w1 = WT + (j + 1) * 52;
      const float* __restrict__ w2 = WT + (j + 2) * 52;
      const float* __restrict__ w3 = WT + (j + 3) * 52;
#define FMA4(h)                   \
  a##h = fmaf(xv0, w0[h], a##h);  \
  a##h = fmaf(xv1, w1[h], a##h);  \
  a##h = fmaf(xv2, w2[h], a##h);  \
  a##h = fmaf(xv3, w3[h], a##h);
      R50(FMA4)
    }
  }

#define RELUA(h) a##h = fmaxf(a##h, 0.f);
  R50(RELUA)

#define DECLG(h) float g##h = b_ctx[h];
  R50(DECLG)

#define GH(h) g##h = fmaf(av, wh[h], g##h);
#define GJ(j, an) { const float av = an; const float* __restrict__ wh = WHT + (j) * 52; R50(GH) }
  GJ(0, a0) GJ(1, a1) GJ(2, a2) GJ(3, a3) GJ(4, a4)
  GJ(5, a5) GJ(6, a6) GJ(7, a7) GJ(8, a8) GJ(9, a9)
  GJ(10, a10) GJ(11, a11) GJ(12, a12) GJ(13, a13) GJ(14, a14)
  GJ(15, a15) GJ(16, a16) GJ(17, a17) GJ(18, a18) GJ(19, a19)
  GJ(20, a20) GJ(21, a21) GJ(22, a22) GJ(23, a23) GJ(24, a24)
  GJ(25, a25) GJ(26, a26) GJ(27, a27) GJ(28, a28) GJ(29, a29)
  GJ(30, a30) GJ(31, a31) GJ(32, a32) GJ(33, a33) GJ(34, a34)
  GJ(35, a35) GJ(36, a36) GJ(37, a37) GJ(38, a38) GJ(39, a39)
  GJ(40, a40) GJ(41, a41) GJ(42, a42) GJ(43, a43) GJ(44, a44)
  GJ(45, a45) GJ(46, a46) GJ(47, a47) GJ(48, a48) GJ(49, a49)

  const int row = blockIdx.x * 256 + tid;
  float* __restrict__ gr = g + (size_t)row * GSTRIDE;
  *reinterpret_cast<float4*>(gr + 0) = make_float4(g0, g1, g2, g3);
  *reinterpret_cast<float4*>(gr + 4) = make_float4(g4, g5, g6, g7);
  *reinterpret_cast<float4*>(gr + 8) = make_float4(g8, g9, g10, g11);
  *reinterpret_cast<float4*>(gr + 12) = make_float4(g12, g13, g14, g15);
  *reinterpret_cast<float4*>(gr + 16) = make_float4(g16, g17, g18, g19);
  *reinterpret_cast<float4*>(gr + 20) = make_float4(g20, g21, g22, g23);
  *reinterpret_cast<float4*>(gr + 24) = make_float4(g24, g25, g26, g27);
  *reinterpret_cast<float4*>(gr + 28) = make_float4(g28, g29, g30, g31);
  *reinterpret_cast<float4*>(gr + 32) = make_float4(g32, g33, g34, g35);
  *reinterpret_cast<float4*>(gr + 36) = make_float4(g36, g37, g38, g39);
  *reinterpret_cast<float4*>(gr + 40) = make_float4(g40, g41, g42, g43);
  *reinterpret_cast<float4*>(gr + 44) = make_float4(g44, g45, g46, g47);
  *reinterpret_cast<float2*>(gr + 48) = make_float2(g48, g49);
}

// ---------------- K2: per-batch recurrence (512 blocks x 1 wave) -----------
// c broadcast via wave-uniform float4 LDS reads (13 DS ops/iter, no
// readlane, no SALU hazards). Weights pinned. Single-wave DS ordering
// makes the end-of-iter c_lds write visible to next iter without barriers.
// lanes 0-49: c; 50-54: keys; 55-59: q.
__global__ __launch_bounds__(64, 1) void k2_rec(
    const float* __restrict__ g, const float* __restrict__ WK2T,
    const float* __restrict__ bias2, const float* __restrict__ first_context,
    float* __restrict__ ctxg, float* __restrict__ keyg,
    float* __restrict__ qg) {
  __shared__ __align__(16) float c_lds[64];
  const int b = blockIdx.x;
  const int lane = threadIdx.x;

#define WDECL(j)                            \
  float w##j = WK2T[(j) * 64 + lane];       \
  asm volatile("" : "+v"(w##j));
  R50(WDECL)
  const float bias = bias2[lane];

  const float c0v = (lane < HH) ? first_context[lane] : 0.f;
  c_lds[lane] = c0v;
  if (lane < HH) ctxg[((size_t)b * 257 + 0) * HH + lane] = c0v;

  float gvA = (lane < HH) ? g[((size_t)0 * BB + b) * GSTRIDE + lane] : 0.f;
  float gvB = (lane < HH) ? g[((size_t)1 * BB + b) * GSTRIDE + lane] : 0.f;
  float gvC = (lane < HH) ? g[((size_t)2 * BB + b) * GSTRIDE + lane] : 0.f;

#define DOTQ(j0, j1, j2, j3)                                            \
  {                                                                     \
    const float4 cv = *reinterpret_cast<const float4*>(&c_lds[j0]);     \
    acc0 = fmaf(w##j0, cv.x, acc0);                                     \
    acc1 = fmaf(w##j1, cv.y, acc1);                                     \
    acc2 = fmaf(w##j2, cv.z, acc2);                                     \
    acc3 = fmaf(w##j3, cv.w, acc3);                                     \
  }
#define DOT50L                                                          \
  float acc0 = 0.f, acc1 = 0.f, acc2 = 0.f, acc3 = 0.f;                 \
  DOTQ(0, 1, 2, 3) DOTQ(4, 5, 6, 7) DOTQ(8, 9, 10, 11)                  \
  DOTQ(12, 13, 14, 15) DOTQ(16, 17, 18, 19) DOTQ(20, 21, 22, 23)        \
  DOTQ(24, 25, 26, 27) DOTQ(28, 29, 30, 31) DOTQ(32, 33, 34, 35)        \
  DOTQ(36, 37, 38, 39) DOTQ(40, 41, 42, 43) DOTQ(44, 45, 46, 47)        \
  {                                                                     \
    const float2 cv2 = *reinterpret_cast<const float2*>(&c_lds[48]);    \
    acc0 = fmaf(w48, cv2.x, acc0);                                      \
    acc1 = fmaf(w49, cv2.y, acc1);                                      \
  }                                                                     \
  const float acc = (acc0 + acc1) + (acc2 + acc3);

#pragma unroll 1
  for (int t = 0; t < TT; ++t) {
    float gvn = 0.f;
    if (lane < HH && (t + 3) < TT)
      gvn = g[((size_t)(t + 3) * BB + b) * GSTRIDE + lane];

    DOT50L

    if (lane >= HH && lane < HH + KK)
      keyg[((size_t)b * KK + (lane - HH)) * 257 + t] = acc + bias;
    if (lane >= HH + KK && lane < HH + 2 * KK && t >= 1)
      qg[((size_t)b * KK + (lane - HH - KK)) * 256 + (t - 1)] = acc + bias;

    const float cn = fmaxf(acc + gvA, 0.f);
    gvA = gvB;
    gvB = gvC;
    gvC = gvn;
    if (lane < HH) ctxg[((size_t)b * 257 + (t + 1)) * HH + lane] = cn;
    c_lds[lane] = cn;  // in-wave DS order: visible to next iter's reads
  }

  {  // tail t = TT: key[TT] (of c_TT) and q[TT-1]
    DOT50L
    if (lane >= HH && lane < HH + KK)
      keyg[((size_t)b * KK + (lane - HH)) * 257 + TT] = acc + bias;
    if (lane >= HH + KK && lane < HH + 2 * KK)
      qg[((size_t)b * KK + (lane - HH - KK)) * 256 + (TT - 1)] = acc + bias;
  }
}

// ---------------- K3: attention + output ----------------
// Block = (b, 32-t chunk), heavy-first. q values pinned resident.
__global__ __launch_bounds__(256, 4) void k3_attn(
    const float* __restrict__ ctxg, const float* __restrict__ keyg,
    const float* __restrict__ qg, const float* __restrict__ W_act,
    const float* __restrict__ b_act, float* __restrict__ out) {
  __shared__ __align__(16) float ct[64 * CTS];

  const int tid = threadIdx.x;
  const int bid = blockIdx.x;
  const int chunk = 7 - (bid >> 9);  // heavy-first
  const int b = bid & 511;
  const int tbase = chunk * 32;
  const int nst = tbase + 33;
  const int ntiles = (nst + 63) >> 6;
  const int wave = tid >> 6;
  const int lane = tid & 63;
  const int qb0 = b * (KK * 256);
  const int kb0 = b * (KK * 257);

#define QL(gn, i, toff)                                  \
  const int t##gn##i = tbase + (toff) + wave * 4 + (i);  \
  float q##gn##i##_0 = qg[qb0 + 0 * 256 + t##gn##i];     \
  float q##gn##i##_1 = qg[qb0 + 1 * 256 + t##gn##i];     \
  float q##gn##i##_2 = qg[qb0 + 2 * 256 + t##gn##i];     \
  float q##gn##i##_3 = qg[qb0 + 3 * 256 + t##gn##i];     \
  float q##gn##i##_4 = qg[qb0 + 4 * 256 + t##gn##i];     \
  asm volatile("" : "+v"(q##gn##i##_0), "+v"(q##gn##i##_1), \
                    "+v"(q##gn##i##_2), "+v"(q##gn##i##_3), \
                    "+v"(q##gn##i##_4));
  QL(A, 0, 0) QL(A, 1, 0) QL(A, 2, 0) QL(A, 3, 0)
  QL(B, 0, 16) QL(B, 1, 16) QL(B, 2, 16) QL(B, 3, 16)

#define ZSO(gn, i) float s_##gn##i = 0.f, o_##gn##i = 0.f;
  G2(ZSO)

  const float wa0 = (lane < HH) ? W_act[0 * HH + lane] : 0.f;
  const float wa1 = (lane < HH) ? W_act[1 * HH + lane] : 0.f;
  const float wa2 = (lane < HH) ? W_act[2 * HH + lane] : 0.f;
  const float wa3 = (lane < HH) ? W_act[3 * HH + lane] : 0.f;
  const float ba0 = b_act[0], ba1 = b_act[1], ba2 = b_act[2], ba3 = b_act[3];

#pragma unroll 1
  for (int tile = 0; tile < ntiles; ++tile) {
    __syncthreads();
    {  // stage ct rows [tile*64, tile*64+64), stride CTS (conflict-free)
      const int r = tid >> 2;
      const int c0 = (tid & 3) * 16;
      const int srow = tile * 64 + r;
      float2* dst = reinterpret_cast<float2*>(ct + r * CTS + c0);
      const float* src = ctxg + ((size_t)b * 257 + srow) * HH;
      const bool sv = (srow < nst);
#pragma unroll
      for (int u = 0; u < 8; ++u) {
        const int c = c0 + u * 2;
        float2 v = make_float2(0.f, 0.f);
        if (sv && c < HH) v = *reinterpret_cast<const float2*>(src + c);
        dst[u] = v;
      }
    }
    __syncthreads();

    const int sbase = tile * 64;
    const int smax = tB3 + 1 - sbase;  // largest valid s-slot for this wave
    if (smax < 0) continue;            // wave-uniform; barriers still met

    const int s = sbase + lane;
    const float kv0 = keyg[kb0 + 0 * 257 + s];
    const float kv1 = keyg[kb0 + 1 * 257 + s];
    const float kv2 = keyg[kb0 + 2 * 257 + s];
    const float kv3 = keyg[kb0 + 3 * 257 + s];
    const float kv4 = keyg[kb0 + 4 * 257 + s];

#define SCORE(gn, i)                              \
  float p_##gn##i;                                \
  {                                               \
    float sc = q##gn##i##_0 * kv0;                \
    sc = fmaf(q##gn##i##_1, kv1, sc);             \
    sc = fmaf(q##gn##i##_2, kv2, sc);             \
    sc = fmaf(q##gn##i##_3, kv3, sc);             \
    sc = fmaf(q##gn##i##_4, kv4, sc);             \
    p_##gn##i = (s <= t##gn##i + 1) ? __expf(sc) : 0.f; \
    s_##gn##i += p_##gn##i;                       \
  }
    G2(SCORE)

    const float* crow = ct + lane;
#define PVB(gn, i, u)                                                        \
  o_##gn##i = fmaf(__int_as_float(__builtin_amdgcn_readlane(                 \
                       __float_as_int(p_##gn##i), sl0 + (u))),               \
                   cv, o_##gn##i);
#define PVSL(u)                                      \
  {                                                  \
    const float cv = crow[(sl0 + (u)) * CTS];        \
    PVB(A, 0, u) PVB(A, 1, u) PVB(A, 2, u) PVB(A, 3, u) \
    PVB(B, 0, u) PVB(B, 1, u) PVB(B, 2, u) PVB(B, 3, u) \
  }
#pragma unroll 1
    for (int sl0 = 0; sl0 < 64; sl0 += 16) {
      if (sl0 > smax) break;
      R16(PVSL)
    }
  }

#define RED5(d)                  \
  v0 += __shfl_xor(v0, d, 64);   \
  v1 += __shfl_xor(v1, d, 64);   \
  v2 += __shfl_xor(v2, d, 64);   \
  v3 += __shfl_xor(v3, d, 64);   \
  st += __shfl_xor(st, d, 64);
#define EPI(gn, i)                                                   \
  {                                                                  \
    float v0 = o_##gn##i * wa0, v1 = o_##gn##i * wa1;                \
    float v2 = o_##gn##i * wa2, v3 = o_##gn##i * wa3;                \
    float st = s_##gn##i;                                            \
    RED5(1) RED5(2) RED5(4) RED5(8) RED5(16) RED5(32)                \
    if (lane == 0) {                                                 \
      const float inv = 1.f / st;                                    \
      *reinterpret_cast<float4*>(out +                               \
          (size_t)((t##gn##i) * BB + b) * AA) =                      \
          make_float4(fmaf(v0, inv, ba0), fmaf(v1, inv, ba1),        \
                      fmaf(v2, inv, ba2), fmaf(v3, inv, ba3));       \
    }                                                                \
  }
  G2(EPI)
}

extern "C" void kernel_launch(void* const* d_in, const int* in_sizes, int n_in,
                              void* d_out, int out_size, void* d_ws,
                              size_t ws_size, hipStream_t stream) {
  const float* x = (const float*)d_in[0];
  const float* W_in = (const float*)d_in[1];
  const float* b_in = (const float*)d_in[2];
  const float* W_ctx = (const float*)d_in[3];
  const float* b_ctx = (const float*)d_in[4];
  const float* W_key = (const float*)d_in[5];
  const float* b_key = (const float*)d_in[6];
  const float* W_q = (const float*)d_in[7];
  const float* b_q = (const float*)d_in[8];
  const float* fc = (const float*)d_in[9];
  const float* W_act = (const float*)d_in[10];
  const float* b_act = (const float*)d_in[11];
  float* out = (float*)d_out;
  float* ws = (float*)d_ws;

  float* WT = ws;                                 // 128*52
  float* WHT = ws + 8192;                         // 50*52
  float* WK2T = ws + 12288;                       // 50*64
  float* bias2 = ws + 15616;                      // 64
  float* g = ws + 16384;                          // 131072*52
  float* ctxg = g + (size_t)131072 * GSTRIDE;     // 512*257*50
  float* keyg = ctxg + (size_t)BB * 257 * HH;     // 512*5*257
  float* qg = keyg + (size_t)BB * KK * 257;       // 512*5*256

  hipLaunchKernelGGL(k0_prep, dim3(26), dim3(256), 0, stream, W_in, W_ctx,
                     W_key, W_q, b_key, b_q, WT, WHT, WK2T, bias2);
  hipLaunchKernelGGL(k1_fused, dim3(512), dim3(256), 0, stream, x, WT, WHT,
                     b_in, b_ctx, g);
  hipLaunchKernelGGL(k2_rec, dim3(512), dim3(64), 0, stream, g, WK2T, bias2,
                     fc, ctxg, keyg, qg);
  hipLaunchKernelGGL(k3_attn, dim3(4096), dim3(256), 0, stream, ctxg, keyg, qg,
                     W_act, b_act, out);
}